// Round 5
// baseline (409.228 us; speedup 1.0000x reference)
//
#include <hip/hip_runtime.h>

typedef __attribute__((ext_vector_type(8))) short bf16x8;
typedef __attribute__((ext_vector_type(4))) short bf16x4;
typedef __attribute__((ext_vector_type(16))) float f32x16;
typedef __attribute__((ext_vector_type(4))) float f32x4;

#define NPTS 32
#define HID 256
#define FANIN 260
#define NKB 17          // 16 h K-blocks (K=16 each) + 1 x/bias block
#define OUTSTRIDE 8192  // NPTS*HID

__device__ __forceinline__ unsigned short f2bf(float f) {
  unsigned u = __builtin_bit_cast(unsigned, f);
  u += 0x7fffu + ((u >> 16) & 1u);  // round-to-nearest-even
  return (unsigned short)(u >> 16);
}

// prep (unchanged, validated): coalesced. grid = 32 p * 8 nb; block 256.
// pack[((p*8 + nb)*17 + kb)*64 + lane], lane decomposed as (m = lane&31,
// g = lane>>5):
//   kb<16:  frag[i] = W[p][nb*32 + m][kb*16 + g*8 + i]
//   kb==16: g==0 -> {W[p][n][256..260), bias[p][n], 0,0,0}; g==1 -> 0
// Under mfma(A=frag, B=hfrag): A[row=m][k=g*8+i] = W[p][row][k]  (exactly
// the A-operand layout; same bytes previously validated as B-operand).
__global__ __launch_bounds__(256) void prep_kernel(
    const float* __restrict__ W, const float* __restrict__ bias,
    bf16x8* __restrict__ pack) {
  __shared__ float wl[32 * FANIN];  // 33.3 KB
  const int p = blockIdx.x >> 3;
  const int nb = blockIdx.x & 7;
  const int t = threadIdx.x;
  const f32x4* src = reinterpret_cast<const f32x4*>(
      W + ((size_t)p * HID + nb * 32) * FANIN);
  for (int i = t; i < 32 * FANIN / 4; i += 256)  // 260%4==0: never crosses rows
    *reinterpret_cast<f32x4*>(wl + i * 4) = src[i];
  __syncthreads();
  const int lane = t & 63;
  const int wv = t >> 6;
  const int m = lane & 31;
  const int g = lane >> 5;
  const float* rowp = wl + m * FANIN;
  for (int kb = wv; kb < NKB; kb += 4) {
    unsigned short e[8];
#pragma unroll
    for (int i = 0; i < 8; ++i) e[i] = 0;
    if (kb < 16) {
      int k0 = kb * 16 + g * 8;
#pragma unroll
      for (int i = 0; i < 8; ++i) e[i] = f2bf(rowp[k0 + i]);
    } else if (g == 0) {
      e[0] = f2bf(rowp[256]);
      e[1] = f2bf(rowp[257]);
      e[2] = f2bf(rowp[258]);
      e[3] = f2bf(rowp[259]);
      e[4] = f2bf(bias[p * HID + nb * 32 + m]);
    }
    bf16x8 v;
#pragma unroll
    for (int i = 0; i < 8; ++i) v[i] = (short)e[i];
    pack[(((size_t)p * 8 + nb) * NKB + kb) * 64 + lane] = v;
  }
}

// enc v4: swapped operands. D = W·h: A = pack frag (rows = hidden-out),
// B = h frag (cols = batch). Lane (b = lane&31, g = lane>>5) holds, for ITS
// batch row b, hidden cols w*32 + {0..3,8..11,16..19,24..27}+4g -> output is
// 4x contiguous f32x4 per lane (16B/lane wide stores, 8 waves storing =
// max in-flight write bytes), and h reads are per-lane-row b128.
// h in LDS [32 batch][256 hid] bf16, XOR swizzle byte ^= (b&7)<<4,
// double-buffered 2x16KB. One lgkm-only barrier per step.
__global__ __launch_bounds__(512) void enc_kernel(
    const float* __restrict__ path, const bf16x8* __restrict__ pack,
    float* __restrict__ out) {
  __shared__ __align__(16) char lds[32768];
  const int tid = threadIdx.x;
  const int lane = tid & 63;
  const int w = tid >> 6;     // wave id 0..7 = hidden col-block
  const int b = lane & 31;    // batch row within tile (B-col / D-col)
  const int g = lane >> 5;    // k-group / row-half
  const int b0 = blockIdx.x * 32;
  const int swzb = (b & 7) << 4;

  {  // zero h buffer 0 (h0 = 0)
    f32x4 z = {0.0f, 0.0f, 0.0f, 0.0f};
    *reinterpret_cast<f32x4*>(lds + tid * 32) = z;
    *reinterpret_cast<f32x4*>(lds + tid * 32 + 16) = z;
  }

  const f32x4* prow =
      reinterpret_cast<const f32x4*>(path + (size_t)(b0 + b) * 128);
  float* outbase = out + (size_t)(b0 + b) * OUTSTRIDE + w * 32;

  bf16x8 BC[NKB];
  {
    const bf16x8* Bp0 = pack + (size_t)w * NKB * 64 + lane;
#pragma unroll
    for (int kb = 0; kb < NKB; ++kb) BC[kb] = Bp0[kb * 64];
  }
  __syncthreads();

  for (int p = 0; p < NPTS; ++p) {
    const int pn = (p + 1 < NPTS) ? p + 1 : 0;  // clamp: harmless re-read
    const bf16x8* Anp = pack + ((size_t)(pn * 8 + w) * NKB) * 64 + lane;
    f32x4 px = prow[p];
    f32x16 acc0, acc1;
#pragma unroll
    for (int i = 0; i < 16; ++i) {
      acc0[i] = 0.0f;
      acc1[i] = 0.0f;
    }
    const char* hb = lds + (p & 1) * 16384;
#pragma unroll
    for (int kb = 0; kb < 16; ++kb) {
      bf16x8 hfrag = *reinterpret_cast<const bf16x8*>(
          hb + b * 512 + ((kb * 32 + g * 16) ^ swzb));
      if (kb & 1)
        acc1 = __builtin_amdgcn_mfma_f32_32x32x16_bf16(BC[kb], hfrag, acc1, 0, 0, 0);
      else
        acc0 = __builtin_amdgcn_mfma_f32_32x32x16_bf16(BC[kb], hfrag, acc0, 0, 0, 0);
      BC[kb] = Anp[kb * 64];  // rolling prefetch; WAR reg-reuse is free
    }
    bf16x8 bx;  // x/bias B-frag: g==0 lanes hold [x0..x3, 1.0, 0,0,0]
#pragma unroll
    for (int i = 0; i < 8; ++i) bx[i] = 0;
    if (g == 0) {
      bx[0] = (short)f2bf(px[0]);
      bx[1] = (short)f2bf(px[1]);
      bx[2] = (short)f2bf(px[2]);
      bx[3] = (short)f2bf(px[3]);
      bx[4] = (short)0x3F80;  // 1.0 pairs with bias row in A
    }
    acc0 = __builtin_amdgcn_mfma_f32_32x32x16_bf16(BC[16], bx, acc0, 0, 0, 0);
    BC[16] = Anp[16 * 64];

    char* hn = lds + ((p + 1) & 1) * 16384;
    float* outp = outbase + p * 256;
#pragma unroll
    for (int r4 = 0; r4 < 4; ++r4) {
      const int hid0 = r4 * 8 + 4 * g;  // D rows 4r4*2.. : {0,8,16,24}+4g
      f32x4 v;
#pragma unroll
      for (int j = 0; j < 4; ++j)
        v[j] = fmaxf(acc0[r4 * 4 + j] + acc1[r4 * 4 + j], 0.0f);
      __builtin_nontemporal_store(v, reinterpret_cast<f32x4*>(outp + hid0));
      bf16x4 hv;
#pragma unroll
      for (int j = 0; j < 4; ++j) hv[j] = (short)f2bf(v[j]);
      *reinterpret_cast<bf16x4*>(
          hn + b * 512 + (((w * 32 + hid0) * 2) ^ swzb)) = hv;
    }
    asm volatile("s_waitcnt lgkmcnt(0)" ::: "memory");
    __builtin_amdgcn_s_barrier();
  }
}

extern "C" void kernel_launch(void* const* d_in, const int* in_sizes, int n_in,
                              void* d_out, int out_size, void* d_ws,
                              size_t ws_size, hipStream_t stream) {
  const float* path = (const float*)d_in[0];  // [8192][128]
  const float* W = (const float*)d_in[1];     // [32][256][260]
  const float* bias = (const float*)d_in[2];  // [32][256]
  float* out = (float*)d_out;                 // [8192][8192]
  bf16x8* pack = (bf16x8*)d_ws;               // 32*8*17*64 frags = 4.45 MB

  prep_kernel<<<256, 256, 0, stream>>>(W, bias, pack);
  enc_kernel<<<256, 512, 0, stream>>>(path, pack, out);
}

// Round 6
// 97.685 us; speedup vs baseline: 4.1893x; 4.1893x over previous
//
#include <hip/hip_runtime.h>

typedef __attribute__((ext_vector_type(8))) short bf16x8;
typedef __attribute__((ext_vector_type(16))) float f32x16;
typedef __attribute__((ext_vector_type(4))) float f32x4;

#define NPTS 32
#define HID 256
#define FANIN 260
#define NKB 17          // 16 h K-blocks (K=16 each) + 1 x/bias block
#define OUTSTRIDE 8192  // NPTS*HID

__device__ __forceinline__ unsigned short f2bf(float f) {
  unsigned u = __builtin_bit_cast(unsigned, f);
  u += 0x7fffu + ((u >> 16) & 1u);  // round-to-nearest-even
  return (unsigned short)(u >> 16);
}

// prep (validated): coalesced. grid = 32 p * 8 nb; block 256.
// pack[((p*8 + nb)*17 + kb)*64 + lane], (m = lane&31, g = lane>>5):
//   kb<16:  frag[i] = W[p][nb*32 + m][kb*16 + g*8 + i]
//   kb==16: g==0 -> {W[p][m][256..260), bias[p][m], 0,0,0}; g==1 -> 0
__global__ __launch_bounds__(256) void prep_kernel(
    const float* __restrict__ W, const float* __restrict__ bias,
    bf16x8* __restrict__ pack) {
  __shared__ float wl[32 * FANIN];  // 33.3 KB
  const int p = blockIdx.x >> 3;
  const int nb = blockIdx.x & 7;
  const int t = threadIdx.x;
  const f32x4* src = reinterpret_cast<const f32x4*>(
      W + ((size_t)p * HID + nb * 32) * FANIN);
  for (int i = t; i < 32 * FANIN / 4; i += 256)  // 260%4==0: never crosses rows
    *reinterpret_cast<f32x4*>(wl + i * 4) = src[i];
  __syncthreads();
  const int lane = t & 63;
  const int wv = t >> 6;
  const int m = lane & 31;
  const int g = lane >> 5;
  const float* rowp = wl + m * FANIN;
  for (int kb = wv; kb < NKB; kb += 4) {
    unsigned short e[8];
#pragma unroll
    for (int i = 0; i < 8; ++i) e[i] = 0;
    if (kb < 16) {
      int k0 = kb * 16 + g * 8;
#pragma unroll
      for (int i = 0; i < 8; ++i) e[i] = f2bf(rowp[k0 + i]);
    } else if (g == 0) {
      e[0] = f2bf(rowp[256]);
      e[1] = f2bf(rowp[257]);
      e[2] = f2bf(rowp[258]);
      e[3] = f2bf(rowp[259]);
      e[4] = f2bf(bias[p * HID + nb * 32 + m]);
    }
    bf16x8 v;
#pragma unroll
    for (int i = 0; i < 8; ++i) v[i] = (short)e[i];
    pack[(((size_t)p * 8 + nb) * NKB + kb) * 64 + lane] = v;
  }
}

// enc v6: R2 orientation (A = h batch-rows, B = W; D col = hidden, row =
// batch) + staged line-wide stores. Epilogue stages fp32 tile to LDS; after
// the lgkm-only barrier ALL 8 waves stream it out as dwordx4, 1KB contiguous
// per wave per inst (full 64B lines -> no write amplification, 4 store
// insts/thread/step). h bf16 double-buf 2x16KB @[0,32K); stage 2x32KB
// @[32K,96K). launch_bounds(512,2): VGPR cap 256, no spill (R5 lesson).
__global__ __launch_bounds__(512, 2) void enc_kernel(
    const float* __restrict__ path, const bf16x8* __restrict__ pack,
    float* __restrict__ out) {
  __shared__ __align__(16) char lds[98304];
  const int tid = threadIdx.x;
  const int lane = tid & 63;
  const int w = tid >> 6;   // wave id 0..7 = hidden col-block
  const int col = lane & 31;  // A-row (batch) / B-col / D-col (hidden)
  const int g = lane >> 5;    // k-group
  const int b0 = blockIdx.x * 32;
  const int swz = col << 4;

  {  // zero h buffer 0 (h0 = 0)
    f32x4 z = {0.0f, 0.0f, 0.0f, 0.0f};
    *reinterpret_cast<f32x4*>(lds + tid * 32) = z;
    *reinterpret_cast<f32x4*>(lds + tid * 32 + 16) = z;
  }

  const float4* prow =
      reinterpret_cast<const float4*>(path + (size_t)(b0 + col) * 128);
  float* outbase = out + (size_t)b0 * OUTSTRIDE;

  bf16x8 BC[NKB];
  {
    const bf16x8* Bp0 = pack + (size_t)w * NKB * 64 + lane;
#pragma unroll
    for (int kb = 0; kb < NKB; ++kb) BC[kb] = Bp0[kb * 64];
  }
  float4 px = prow[0];
  __syncthreads();

  for (int p = 0; p < NPTS; ++p) {
    const int pn = (p + 1 < NPTS) ? p + 1 : 0;  // clamp: harmless re-read
    const bf16x8* Bnp = pack + ((size_t)(pn * 8 + w) * NKB) * 64 + lane;
    f32x16 acc0, acc1;
#pragma unroll
    for (int i = 0; i < 16; ++i) {
      acc0[i] = 0.0f;
      acc1[i] = 0.0f;
    }
    const char* hb = lds + (p & 1) * 16384;
#pragma unroll
    for (int kb = 0; kb < 16; ++kb) {
      bf16x8 a = *reinterpret_cast<const bf16x8*>(
          hb + col * 512 + ((kb * 32 + g * 16) ^ swz));
      if (kb & 1)
        acc1 = __builtin_amdgcn_mfma_f32_32x32x16_bf16(a, BC[kb], acc1, 0, 0, 0);
      else
        acc0 = __builtin_amdgcn_mfma_f32_32x32x16_bf16(a, BC[kb], acc0, 0, 0, 0);
      BC[kb] = Bnp[kb * 64];  // rolling prefetch for step p+1
    }
    bf16x8 ax;  // x/bias A-frag: g==0 lanes hold [x0..x3, 1.0, 0,0,0]
#pragma unroll
    for (int i = 0; i < 8; ++i) ax[i] = 0;
    if (g == 0) {
      ax[0] = (short)f2bf(px.x);
      ax[1] = (short)f2bf(px.y);
      ax[2] = (short)f2bf(px.z);
      ax[3] = (short)f2bf(px.w);
      ax[4] = (short)0x3F80;  // 1.0 pairs with bias row in B
    }
    acc0 = __builtin_amdgcn_mfma_f32_32x32x16_bf16(ax, BC[16], acc0, 0, 0, 0);
    BC[16] = Bnp[16 * 64];
    px = prow[pn];  // rolling x prefetch

    // epilogue: relu; stage fp32 to LDS; bf16 h_next to other h buf
    char* hn = lds + ((p + 1) & 1) * 16384;
    float* st = reinterpret_cast<float*>(lds + 32768 + (p & 1) * 32768);
#pragma unroll
    for (int r = 0; r < 16; ++r) {
      int rr = (r & 3) + 8 * (r >> 2) + 4 * g;  // C/D row = batch (verified)
      float v = fmaxf(acc0[r] + acc1[r], 0.0f);
      st[rr * 256 + w * 32 + col] = v;  // conflict-free (contig dwords)
      *reinterpret_cast<unsigned short*>(
          hn + rr * 512 + (((w * 32 + col) * 2) ^ (rr << 4))) = f2bf(v);
    }
    asm volatile("s_waitcnt lgkmcnt(0)" ::: "memory");
    __builtin_amdgcn_s_barrier();

    // store phase: all 8 waves; 1KB contiguous per wave per inst
    const f32x4* stf =
        reinterpret_cast<const f32x4*>(lds + 32768 + (p & 1) * 32768);
    float* ob = outbase + p * 256;
#pragma unroll
    for (int s = 0; s < 4; ++s) {
      int i = s * 512 + tid;
      f32x4 v = stf[i];
      int r = i >> 6;          // batch row 0..31
      int c = (i & 63) << 2;   // float col 0..255
      __builtin_nontemporal_store(
          v, reinterpret_cast<f32x4*>(ob + (size_t)r * OUTSTRIDE + c));
    }
  }
}

extern "C" void kernel_launch(void* const* d_in, const int* in_sizes, int n_in,
                              void* d_out, int out_size, void* d_ws,
                              size_t ws_size, hipStream_t stream) {
  const float* path = (const float*)d_in[0];  // [8192][128]
  const float* W = (const float*)d_in[1];     // [32][256][260]
  const float* bias = (const float*)d_in[2];  // [32][256]
  float* out = (float*)d_out;                 // [8192][8192]
  bf16x8* pack = (bf16x8*)d_ws;               // 32*8*17*64 frags = 4.45 MB

  prep_kernel<<<256, 256, 0, stream>>>(W, bias, pack);
  enc_kernel<<<256, 512, 0, stream>>>(path, pack, out);
}